// Round 7
// baseline (1857.770 us; speedup 1.0000x reference)
//
#include <hip/hip_runtime.h>
#include <hip/hip_bf16.h>
#include <math.h>

// MDN-RNN: B=128, T=512, Z=32, A=3, H=256, K=5, IN=35, 4H=1024, MDN=325
#define T_LEN 512
#define B_SZ  128
#define H_DIM 256
#define G_DIM 1024
#define IN_D  35
#define MDN_D 325
#define K_MIX 5

#define NSLICE 4     // gate-dim slices per group (each owns 64 h-cols x 4 gates)
#define BG     2     // batches per group
#define NGRP   64    // 128 / BG   -> 256 blocks total = 1/CU

// d_out layout: log_pi[B,T,5] | mu[B,T,5,32] | sigma[B,T,5,32] | c[B,256] | h[B,256]
static constexpr long OFF_MU    = 327680L;
static constexpr long OFF_SIGMA = 10813440L;
static constexpr long OFF_C     = 21299200L;
static constexpr long OFF_H     = 21331968L;

// ws layout (~34 MB; ws >= 64 MiB proven in round 1)
static constexpr size_t WS_OUT = 0;          // bf16 outs: B*T*H*2 = 33,554,432 B
static constexpr size_t WS_HG  = 33554432;   // 64 grp * 2 par * 2 b * 256 f32 = 512 KB

typedef unsigned uint2v  __attribute__((ext_vector_type(2)));
typedef float    float2v __attribute__((ext_vector_type(2)));
typedef float    float4v __attribute__((ext_vector_type(4)));

__device__ __forceinline__ float fast_sigmoid(float x) { return 1.0f / (1.0f + __expf(-x)); }
__device__ __forceinline__ float fast_tanh(float x) {
    return 1.0f - 2.0f / (__expf(2.0f * x) + 1.0f);
}

// acc.lo += w.lo*h.lo ; acc.hi += w.hi*h.lo   (broadcast LOW half of h-pair)
__device__ __forceinline__ void pk_fma_lo(float2v& acc, float2v w, float2v h) {
    asm("v_pk_fma_f32 %0, %1, %2, %0 op_sel:[0,0,0] op_sel_hi:[1,0,1]"
        : "+v"(acc) : "v"(w), "v"(h));
}
// acc.lo += w.lo*h.hi ; acc.hi += w.hi*h.hi   (broadcast HIGH half of h-pair)
__device__ __forceinline__ void pk_fma_hi(float2v& acc, float2v w, float2v h) {
    asm("v_pk_fma_f32 %0, %1, %2, %0 op_sel:[0,1,0] op_sel_hi:[1,1,1]"
        : "+v"(acc) : "v"(w), "v"(h));
}

// 256 blocks (group=bid&63, slice=bid>>6), 512 threads.
// Octet (8 lanes) = h-col j; lane (kq,u) = gates {u,u+2} of col j, k-chunk kq.
// After kq-butterfly + one xor-4 swap every lane holds all 4 gate sums -> nonlin
// in-register (no B2, no g_red). h exchange: tagged self-validating dwords
// (t&3 in 2 LSBs), double-buffered h_lds by parity -> ONE barrier per step.
// Pollers (tid<384, 1 dword each) use 2-deep pipelined polling; stagers (wave 6)
// run a 3-phase x pipeline (issue t+2 -> LDS-write t+1 -> read t).
__global__ __launch_bounds__(512, 1) void lstm7_kernel(
    const float* __restrict__ z_t, const float* __restrict__ a_t,
    const float* __restrict__ Wx,  const float* __restrict__ Wh,
    const float* __restrict__ bias,
    float* __restrict__ h_glb,
    __hip_bfloat16* __restrict__ outs,
    float* __restrict__ out_c, float* __restrict__ out_h)
{
    const int bid = blockIdx.x;
    const int gr  = bid & 63;
    const int s   = bid >> 6;
    const int tid = threadIdx.x;
    const int kq  = tid & 3;               // k-chunk [kq*64, kq*64+64)
    const int u   = (tid >> 2) & 1;        // gate set {u, u+2}
    const int j   = tid >> 3;              // h-col within slice, 0..63
    const int cu0 = u * 256 + s * 64 + j;        // gate u column
    const int cu1 = (u + 2) * 256 + s * 64 + j;  // gate u+2 column

    __shared__ __align__(16) float h_lds[2][BG][4][68];  // [parity][b][kq sect (+4 pad)]
    __shared__ __align__(16) float x_lds[2][BG][44];     // [parity][b][35 + zero pad]

    for (int i = tid; i < 2 * BG * 4 * 68; i += 512) ((float*)h_lds)[i] = 0.0f; // h(-1)=0
    if (tid < 2 * BG * 9) {   // zero x pads [35..43] in both parities/batches
        int buf = tid / 18, r = tid % 18, b = r / 9, k = 35 + r % 9;
        x_lds[buf][b][k] = 0.0f;
    }

    // ---- persistent weights in VGPRs (loaded once, pinned vs remat) ----
    float2v W2[64];
    #pragma unroll
    for (int i = 0; i < 64; ++i) {
        const size_t r = (size_t)(kq * 64 + i) * G_DIM;
        W2[i].x = Wh[r + cu0];
        W2[i].y = Wh[r + cu1];
    }
    float2v X2[10];
    #pragma unroll
    for (int i = 0; i < 10; ++i) {
        int xk = kq * 10 + i;
        bool ok = (xk < IN_D);
        X2[i].x = ok ? Wx[(size_t)xk * G_DIM + cu0] : 0.0f;
        X2[i].y = ok ? Wx[(size_t)xk * G_DIM + cu1] : 0.0f;
    }
    #pragma unroll
    for (int i = 0; i < 64; ++i) asm volatile("" : "+v"(W2[i]));
    #pragma unroll
    for (int i = 0; i < 10; ++i) asm volatile("" : "+v"(X2[i]));

    // bias for the 4 gates of col j (added once, post-reduce)
    const float bci = bias[0 * 256 + s * 64 + j];
    const float bcf = bias[1 * 256 + s * 64 + j];
    const float bcg = bias[2 * 256 + s * 64 + j];
    const float bco = bias[3 * 256 + s * 64 + j];
    float c0 = 0.0f, c1 = 0.0f;            // cell state, replicated per octet

    // poller mapping (tid < 384): one foreign dword each
    const int pb  = (tid >= 192) ? 1 : 0;
    const int pp  = tid - 192 * pb;                     // 0..191
    const int pkk = pp + ((pp >= s * 64) ? 64 : 0);     // skip own 64-chunk

    // stager mapping (wave 6 head): 70 threads, 3-phase x pipeline
    const int  sq    = tid - 384;
    const bool is_st = (sq >= 0 && sq < 2 * IN_D);
    const int  sb    = (sq >= IN_D) ? 1 : 0;
    const int  sk    = sq - IN_D * sb;
    float xreg = 0.0f;

    const int batch0 = gr * BG;
    float* hg = h_glb + (size_t)gr * (2 * BG * H_DIM);   // [2][BG][256]

    // prologue: x(0) -> slot 0 direct; issue x(1) -> xreg
    if (is_st) {
        x_lds[0][sb][sk] = (sk < 32)
            ? z_t[((size_t)(batch0 + sb) * T_LEN + 0) * 32 + sk]
            : a_t[((size_t)(batch0 + sb) * T_LEN + 0) * 3 + (sk - 32)];
        xreg = (sk < 32)
            ? z_t[((size_t)(batch0 + sb) * T_LEN + 1) * 32 + sk]
            : a_t[((size_t)(batch0 + sb) * T_LEN + 1) * 3 + (sk - 32)];
    }
    __syncthreads();

    for (int t = 0; t < T_LEN; ++t) {
        // ---- (A) pipelined poll of one foreign tagged dword (h(t-1)) ----
        if (t > 0 && tid < 384) {
            const unsigned want = (unsigned)((t - 1) & 3);
            const float* ap = hg + ((t - 1) & 1) * (BG * H_DIM) + pb * H_DIM + pkk;
            unsigned v0, v1, got;
            asm volatile("global_load_dword %0, %1, off sc0 sc1"
                         : "=v"(v0) : "v"(ap) : "memory");
            for (;;) {
                asm volatile("global_load_dword %0, %1, off sc0 sc1"
                             : "=v"(v1) : "v"(ap) : "memory");
                asm volatile("s_waitcnt vmcnt(1)" : "+v"(v0) :: "memory");
                if ((v0 & 3u) == want) { got = v0; break; }
                asm volatile("global_load_dword %0, %1, off sc0 sc1"
                             : "=v"(v0) : "v"(ap) : "memory");
                asm volatile("s_waitcnt vmcnt(1)" : "+v"(v1) :: "memory");
                if ((v1 & 3u) == want) { got = v1; break; }
            }
            asm volatile("s_waitcnt vmcnt(0)" ::: "memory");
            h_lds[(t - 1) & 1][pb][pkk >> 6][pkk & 63] = __uint_as_float(got);
        }
        __syncthreads();   // the ONE barrier: h_lds[(t-1)&1] + x_lds[t&1] ready

        // ---- (B) packed FMA: 2 batches x (gate u, gate u+2) x 64 k ----
        float2v acc0 = {0.0f, 0.0f}, acc1 = {0.0f, 0.0f};
        {
            const float4v* hp0 = (const float4v*)h_lds[(t + 1) & 1][0][kq];
            const float4v* hp1 = (const float4v*)h_lds[(t + 1) & 1][1][kq];
            #pragma unroll
            for (int i4 = 0; i4 < 16; ++i4) {
                float4v hv0 = hp0[i4];
                float4v hv1 = hp1[i4];
                float2v h0lo = __builtin_shufflevector(hv0, hv0, 0, 1);
                float2v h0hi = __builtin_shufflevector(hv0, hv0, 2, 3);
                float2v h1lo = __builtin_shufflevector(hv1, hv1, 0, 1);
                float2v h1hi = __builtin_shufflevector(hv1, hv1, 2, 3);
                pk_fma_lo(acc0, W2[4*i4+0], h0lo); pk_fma_lo(acc1, W2[4*i4+0], h1lo);
                pk_fma_hi(acc0, W2[4*i4+1], h0lo); pk_fma_hi(acc1, W2[4*i4+1], h1lo);
                pk_fma_lo(acc0, W2[4*i4+2], h0hi); pk_fma_lo(acc1, W2[4*i4+2], h1hi);
                pk_fma_hi(acc0, W2[4*i4+3], h0hi); pk_fma_hi(acc1, W2[4*i4+3], h1hi);
            }
            #pragma unroll
            for (int i = 0; i < 5; ++i) {
                float2v xv0 = *(const float2v*)&x_lds[t & 1][0][kq * 10 + 2 * i];
                float2v xv1 = *(const float2v*)&x_lds[t & 1][1][kq * 10 + 2 * i];
                pk_fma_lo(acc0, X2[2*i],   xv0); pk_fma_lo(acc1, X2[2*i],   xv1);
                pk_fma_hi(acc0, X2[2*i+1], xv0); pk_fma_hi(acc1, X2[2*i+1], xv1);
            }
        }
        float a00 = acc0.x, a01 = acc0.y;   // b0: gate u, gate u+2
        float a10 = acc1.x, a11 = acc1.y;   // b1
        // kq butterfly (masks 1,2) -> full k-sums
        a00 += __shfl_xor(a00, 1, 64); a00 += __shfl_xor(a00, 2, 64);
        a01 += __shfl_xor(a01, 1, 64); a01 += __shfl_xor(a01, 2, 64);
        a10 += __shfl_xor(a10, 1, 64); a10 += __shfl_xor(a10, 2, 64);
        a11 += __shfl_xor(a11, 1, 64); a11 += __shfl_xor(a11, 2, 64);
        // u-swap (mask 4): receive partner's two gates
        float r00 = __shfl_xor(a00, 4, 64);
        float r01 = __shfl_xor(a01, 4, 64);
        float r10 = __shfl_xor(a10, 4, 64);
        float r11 = __shfl_xor(a11, 4, 64);
        // assemble i,f,g,o (+bias once)
        float gi0 = (u ? r00 : a00) + bci, gf0 = (u ? a00 : r00) + bcf;
        float gg0 = (u ? r01 : a01) + bcg, go0 = (u ? a01 : r01) + bco;
        float gi1 = (u ? r10 : a10) + bci, gf1 = (u ? a10 : r10) + bcf;
        float gg1 = (u ? r11 : a11) + bcg, go1 = (u ? a11 : r11) + bco;

        // ---- (C) nonlin (redundant per octet) + tagged publish ----
        float iv0 = fast_sigmoid(gi0), fv0 = fast_sigmoid(gf0), ov0 = fast_sigmoid(go0);
        float gv0 = fast_tanh(gg0);
        c0 = fmaf(fv0, c0, iv0 * gv0);
        float hv0 = ov0 * fast_tanh(c0);
        float iv1 = fast_sigmoid(gi1), fv1 = fast_sigmoid(gf1), ov1 = fast_sigmoid(go1);
        float gv1 = fast_tanh(gg1);
        c1 = fmaf(fv1, c1, iv1 * gv1);
        float hv1 = ov1 * fast_tanh(c1);

        if (kq == 0) {   // lane u publishes batch u of col j
            float hvu = u ? hv1 : hv0;
            float cu  = u ? c1 : c0;
            unsigned tu = (__float_as_uint(hvu) & ~3u) | (unsigned)(t & 3);
            float* dst = hg + (t & 1) * (BG * H_DIM) + u * H_DIM + s * 64 + j;
            asm volatile("global_store_dword %0, %1, off sc0 sc1"
                         :: "v"(dst), "v"(tu) : "memory");
            h_lds[t & 1][u][s][j] = __uint_as_float(tu);   // own slice: no IC trip
            outs[((size_t)(batch0 + u) * T_LEN + t) * H_DIM + s * 64 + j] =
                __float2bfloat16(hvu);
            if (t == T_LEN - 1) {
                out_c[(batch0 + u) * H_DIM + s * 64 + j] = cu;
                out_h[(batch0 + u) * H_DIM + s * 64 + j] = hvu;
            }
        }
        // ---- (C) stagers: LDS-write x(t+1), issue x(t+2) ----
        if (is_st) {
            x_lds[(t + 1) & 1][sb][sk] = xreg;
            if (t + 2 < T_LEN)
                xreg = (sk < 32)
                    ? z_t[((size_t)(batch0 + sb) * T_LEN + (t + 2)) * 32 + sk]
                    : a_t[((size_t)(batch0 + sb) * T_LEN + (t + 2)) * 3 + (sk - 32)];
        }
        // no trailing barrier: pollers write the OTHER h_lds parity next step
    }
}

// mdn = outputs(bf16) @ Wd + bd, fused log_softmax(log_pi) and exp(log_sigma)+1e-6.
__global__ __launch_bounds__(256, 1) void mdn_kernel(
    const unsigned short* __restrict__ outputs, const float* __restrict__ Wd,
    const float* __restrict__ bd, float* __restrict__ out)
{
    __shared__ __align__(16) float hT[H_DIM * 16];   // hT[k*16 + r]
    __shared__ float lp[16][K_MIX];

    const int tid = threadIdx.x;
    const long row0 = (long)blockIdx.x * 16;

    for (int idx = tid; idx < H_DIM * 16; idx += 256) {
        int r = idx >> 8;
        int k = idx & (H_DIM - 1);
        unsigned int u = outputs[(row0 + r) * H_DIM + k];
        hT[k * 16 + r] = __uint_as_float(u << 16);
    }
    __syncthreads();

    const int  cA = tid;
    const int  cB = tid + 256;
    const bool vB = (cB < MDN_D);
    const float bA = bd[cA];
    const float bB = vB ? bd[cB] : 0.0f;
    float accA[16], accB[16];
    #pragma unroll
    for (int r = 0; r < 16; ++r) { accA[r] = bA; accB[r] = bB; }

    for (int k = 0; k < H_DIM; ++k) {
        float wA = Wd[(size_t)k * MDN_D + cA];
        float wB = vB ? Wd[(size_t)k * MDN_D + cB] : 0.0f;
        const float4* hp = (const float4*)(hT + k * 16);
        float4 h0 = hp[0], h1 = hp[1], h2 = hp[2], h3 = hp[3];
        float hr[16] = { h0.x,h0.y,h0.z,h0.w, h1.x,h1.y,h1.z,h1.w,
                         h2.x,h2.y,h2.z,h2.w, h3.x,h3.y,h3.z,h3.w };
        #pragma unroll
        for (int r = 0; r < 16; ++r) {
            accA[r] = fmaf(hr[r], wA, accA[r]);
            accB[r] = fmaf(hr[r], wB, accB[r]);
        }
    }

    float* out_mu = out + OFF_MU;
    float* out_sg = out + OFF_SIGMA;
    #pragma unroll
    for (int r = 0; r < 16; ++r) {
        long row = row0 + r;
        float v = accA[r];
        if (cA < K_MIX)            lp[r][cA] = v;
        else if (cA < K_MIX + 160) out_mu[row * 160 + (cA - K_MIX)] = v;
        else                       out_sg[row * 160 + (cA - 165)]   = __expf(v) + 1e-6f;
        if (vB)                    out_sg[row * 160 + (cB - 165)]   = __expf(accB[r]) + 1e-6f;
    }
    __syncthreads();

    if (tid < 16) {
        int r = tid;
        long row = row0 + r;
        float v0 = lp[r][0], v1 = lp[r][1], v2 = lp[r][2], v3 = lp[r][3], v4 = lp[r][4];
        float m = fmaxf(fmaxf(fmaxf(v0, v1), fmaxf(v2, v3)), v4);
        float sum = __expf(v0-m) + __expf(v1-m) + __expf(v2-m) + __expf(v3-m) + __expf(v4-m);
        float ls = m + __logf(sum);
        out[row*5 + 0] = v0 - ls;
        out[row*5 + 1] = v1 - ls;
        out[row*5 + 2] = v2 - ls;
        out[row*5 + 3] = v3 - ls;
        out[row*5 + 4] = v4 - ls;
    }
}

extern "C" void kernel_launch(void* const* d_in, const int* in_sizes, int n_in,
                              void* d_out, int out_size, void* d_ws, size_t ws_size,
                              hipStream_t stream)
{
    const float* z_t = (const float*)d_in[0];
    const float* a_t = (const float*)d_in[1];
    const float* Wx  = (const float*)d_in[2];
    const float* Wh  = (const float*)d_in[3];
    const float* b   = (const float*)d_in[4];
    const float* Wd  = (const float*)d_in[5];
    const float* bd  = (const float*)d_in[6];
    float* out = (float*)d_out;

    char* ws = (char*)d_ws;
    __hip_bfloat16* outs = (__hip_bfloat16*)(ws + WS_OUT);
    float* h_glb         = (float*)(ws + WS_HG);

    lstm7_kernel<<<NGRP * NSLICE, 512, 0, stream>>>(z_t, a_t, Wx, Wh, b,
                                                    h_glb, outs,
                                                    out + OFF_C, out + OFF_H);
    mdn_kernel<<<(B_SZ * T_LEN) / 16, 256, 0, stream>>>((const unsigned short*)outs,
                                                        Wd, bd, out);
}

// Round 8
// 1375.143 us; speedup vs baseline: 1.3510x; 1.3510x over previous
//
#include <hip/hip_runtime.h>
#include <hip/hip_bf16.h>
#include <math.h>

// MDN-RNN: B=128, T=512, Z=32, A=3, H=256, K=5, IN=35, 4H=1024, MDN=325
#define T_LEN 512
#define B_SZ  128
#define H_DIM 256
#define G_DIM 1024
#define IN_D  35
#define MDN_D 325
#define K_MIX 5

#define NSLICE 4     // gate-dim slices per group (each owns 64 h-cols x 4 gates)
#define BG     2     // batches per group
#define NGRP   64    // 128 / BG   -> 256 blocks total = 1/CU

// d_out layout: log_pi[B,T,5] | mu[B,T,5,32] | sigma[B,T,5,32] | c[B,256] | h[B,256]
static constexpr long OFF_MU    = 327680L;
static constexpr long OFF_SIGMA = 10813440L;
static constexpr long OFF_C     = 21299200L;
static constexpr long OFF_H     = 21331968L;

// ws layout (~34 MB; ws >= 64 MiB proven in round 1)
static constexpr size_t WS_OUT = 0;          // bf16 outs: B*T*H*2 = 33,554,432 B
static constexpr size_t WS_HG  = 33554432;   // 64 grp * 2 par * 256 k * 2 b f32 = 256 KB

typedef unsigned uint2v  __attribute__((ext_vector_type(2)));
typedef float    float2v __attribute__((ext_vector_type(2)));
typedef float    float4v __attribute__((ext_vector_type(4)));

__device__ __forceinline__ float fast_sigmoid(float x) { return 1.0f / (1.0f + __expf(-x)); }
__device__ __forceinline__ float fast_tanh(float x) {
    return 1.0f - 2.0f / (__expf(2.0f * x) + 1.0f);
}

// acc.lo += w.lo*h.lo ; acc.hi += w.hi*h.lo   (broadcast LOW half of h-pair)
__device__ __forceinline__ void pk_fma_lo(float2v& acc, float2v w, float2v h) {
    asm("v_pk_fma_f32 %0, %1, %2, %0 op_sel:[0,0,0] op_sel_hi:[1,0,1]"
        : "+v"(acc) : "v"(w), "v"(h));
}
// acc.lo += w.lo*h.hi ; acc.hi += w.hi*h.hi   (broadcast HIGH half of h-pair)
__device__ __forceinline__ void pk_fma_hi(float2v& acc, float2v w, float2v h) {
    asm("v_pk_fma_f32 %0, %1, %2, %0 op_sel:[0,1,0] op_sel_hi:[1,1,1]"
        : "+v"(acc) : "v"(w), "v"(h));
}

// 256 blocks (group=bid&63, slice=bid>>6), 512 threads = 8 waves.
// Wave w: k-chunk cw=w>>1 (64 k), col-pair-half uw=w&1 (pairs uw*64..+64 of 128).
// FOREIGN waves (cw!=s): poll the 64 h-dwordx2 of their chunk from hg (tagged,
// serial vmcnt(0) — these waves issue NO stores, so no ack pollution), stash to
// wave-private LDS, FMA immediately (no barrier). OWN waves (cw==s) = publishers:
// read h from their own wave-private copy, never poll. Partials -> parity-
// double-buffered LDS; ONE __syncthreads/step; publishers gather 4 chunks,
// nonlin BOTH batches (redundant), publish tagged h, stage x via reg pipeline
// (shared-x written + lgkmcnt(0) BEFORE the publish store for ordering).
__global__ __launch_bounds__(512, 1) void lstm8_kernel(
    const float* __restrict__ z_t, const float* __restrict__ a_t,
    const float* __restrict__ Wx,  const float* __restrict__ Wh,
    const float* __restrict__ bias,
    float* __restrict__ h_glb,
    __hip_bfloat16* __restrict__ outs,
    float* __restrict__ out_c, float* __restrict__ out_h)
{
    const int bid  = blockIdx.x;
    const int gr   = bid & 63;
    const int s    = bid >> 6;
    const int tid  = threadIdx.x;
    const int w    = tid >> 6;
    const int lane = tid & 63;
    const int cw   = w >> 1;              // k-chunk [cw*64, cw*64+64)
    const int uw   = w & 1;               // pair half
    const bool own = (cw == s);           // own waves = publishers (2 waves)
    const int P    = uw * 64 + lane;      // global pair in [0,128)
    const int q0   = 2 * P;               // slice cols q0, q0+1
    const int gc0  = (q0 >> 6) * 256 + s * 64 + (q0 & 63);
    const int gc1  = ((q0 + 1) >> 6) * 256 + s * 64 + ((q0 + 1) & 63);

    __shared__ __align__(16) float2v hbuf[8][64];        // wave-private polled h
    __shared__ __align__(16) float  hown[2][2][64][2];   // [uw][par][j][b] (tagged)
    __shared__ __align__(16) float4v part[2][4][2][64];  // [par][chunk][half][pair]
    __shared__ __align__(16) float  x_lds[2][2][36];     // shared x (pollers read)
    __shared__ __align__(16) float  xown[2][2][2][36];   // [uw][par][b][k] private

    // zero x pads (k=35)
    if (tid < 4) x_lds[tid >> 1][tid & 1][35] = 0.0f;
    if (own && lane < 4) xown[uw][lane >> 1][lane & 1][35] = 0.0f;

    // ---- persistent weights (loaded once, pinned) ----
    float2v W2[64];
    #pragma unroll
    for (int i = 0; i < 64; ++i) {
        const size_t r = (size_t)(cw * 64 + i) * G_DIM;
        W2[i].x = Wh[r + gc0];
        W2[i].y = Wh[r + gc1];
    }
    float2v X2[9];
    #pragma unroll
    for (int i = 0; i < 9; ++i) {
        int xk = cw * 9 + i;
        bool ok = (xk < IN_D);
        X2[i].x = ok ? Wx[(size_t)xk * G_DIM + gc0] : 0.0f;
        X2[i].y = ok ? Wx[(size_t)xk * G_DIM + gc1] : 0.0f;
    }
    #pragma unroll
    for (int i = 0; i < 64; ++i) asm volatile("" : "+v"(W2[i]));
    #pragma unroll
    for (int i = 0; i < 9; ++i)  asm volatile("" : "+v"(X2[i]));

    // publisher state: col j = lane, both batches
    float bg0 = 0, bg1 = 0, bg2 = 0, bg3 = 0, cc0 = 0.0f, cc1 = 0.0f;
    if (own) {
        bg0 = bias[0 * 256 + s * 64 + lane];
        bg1 = bias[1 * 256 + s * 64 + lane];
        bg2 = bias[2 * 256 + s * 64 + lane];
        bg3 = bias[3 * 256 + s * 64 + lane];
    }

    const int batch0 = gr * BG;
    float* hg = h_glb + (size_t)gr * 1024;   // [2 par][256 k][2 b] floats

    // ---- x register pipeline (publisher-wave lanes < 35) ----
    const bool is_st = own && (lane < IN_D);
    float xr0 = 0.0f, xr1 = 0.0f;            // x(t+1) for b0, b1
    if (is_st) {
        const int k = lane;
        const size_t r0 = (size_t)(batch0 + 0) * T_LEN;
        const size_t r1 = (size_t)(batch0 + 1) * T_LEN;
        float v00 = (k < 32) ? z_t[(r0 + 0) * 32 + k] : a_t[(r0 + 0) * 3 + (k - 32)];
        float v01 = (k < 32) ? z_t[(r1 + 0) * 32 + k] : a_t[(r1 + 0) * 3 + (k - 32)];
        xown[uw][0][0][k] = v00;
        xown[uw][0][1][k] = v01;
        if (uw == 0) { x_lds[0][0][k] = v00; x_lds[0][1][k] = v01; }
        xr0 = (k < 32) ? z_t[(r0 + 1) * 32 + k] : a_t[(r0 + 1) * 3 + (k - 32)];
        xr1 = (k < 32) ? z_t[(r1 + 1) * 32 + k] : a_t[(r1 + 1) * 3 + (k - 32)];
    }
    __syncthreads();

    for (int t = 0; t < T_LEN; ++t) {
        // ---- (A) obtain h(t-1) and FMA ----
        float2v acc0 = {0.0f, 0.0f}, acc1 = {0.0f, 0.0f};
        if (t > 0) {
            if (!own) {
                // serial tagged poll: this wave's 64 dwordx2, no stores anywhere
                const unsigned want = (unsigned)((t - 1) & 3);
                const float* ap = hg + ((t - 1) & 1) * 512 + (cw * 64 + lane) * 2;
                uint2v u;
                do {
                    asm volatile("global_load_dwordx2 %0, %1, off sc0 sc1\n\t"
                                 "s_waitcnt vmcnt(0)"
                                 : "=v"(u) : "v"(ap) : "memory");
                } while ((u.x & 3u) != want || (u.y & 3u) != want);
                float2v hv; hv.x = __uint_as_float(u.x); hv.y = __uint_as_float(u.y);
                hbuf[w][lane] = hv;   // wave-private; lgkm dependency only
            }
            const float4v* hp = own ? (const float4v*)hown[uw][(t - 1) & 1]
                                    : (const float4v*)hbuf[w];
            #pragma unroll
            for (int i2 = 0; i2 < 32; ++i2) {
                float4v hv = hp[i2];                       // (k:b0,b1, k+1:b0,b1)
                float2v lo = __builtin_shufflevector(hv, hv, 0, 1);
                float2v hi = __builtin_shufflevector(hv, hv, 2, 3);
                pk_fma_lo(acc0, W2[2*i2],     lo);   // b0 * W[k]
                pk_fma_hi(acc1, W2[2*i2],     lo);   // b1 * W[k]
                pk_fma_lo(acc0, W2[2*i2 + 1], hi);   // b0 * W[k+1]
                pk_fma_hi(acc1, W2[2*i2 + 1], hi);   // b1 * W[k+1]
            }
        }
        {
            const float* xb0 = own ? &xown[uw][t & 1][0][cw * 9] : &x_lds[t & 1][0][cw * 9];
            const float* xb1 = own ? &xown[uw][t & 1][1][cw * 9] : &x_lds[t & 1][1][cw * 9];
            #pragma unroll
            for (int i = 0; i < 9; ++i) {
                float2v xx; xx.x = xb0[i]; xx.y = xb1[i];
                pk_fma_lo(acc0, X2[i], xx);
                pk_fma_hi(acc1, X2[i], xx);
            }
        }
        // ---- (B) write partial (one b128) ----
        {
            float4v pv; pv.x = acc0.x; pv.y = acc0.y; pv.z = acc1.x; pv.w = acc1.y;
            part[t & 1][cw][uw][lane] = pv;
        }
        __syncthreads();   // the ONE barrier per step

        // ---- (C) publishers: gather 4 chunks x 4 gates, nonlin both b, publish ----
        if (own) {
            const int j = lane;
            float gb[4][2];
            #pragma unroll
            for (int g = 0; g < 4; ++g) {
                const int hu = g >> 1, pl = (g & 1) * 32 + (j >> 1), e = j & 1;
                const float* p = (const float*)&part[t & 1][0][hu][pl] + e;
                float s0 = 0.0f, s1 = 0.0f;
                #pragma unroll
                for (int c = 0; c < 4; ++c) {       // chunk stride = 512 floats
                    s0 += p[c * 512];
                    s1 += p[c * 512 + 2];
                }
                gb[g][0] = s0; gb[g][1] = s1;
            }
            float i0 = fast_sigmoid(gb[0][0] + bg0), f0 = fast_sigmoid(gb[1][0] + bg1);
            float g0 = fast_tanh(gb[2][0] + bg2),    o0 = fast_sigmoid(gb[3][0] + bg3);
            cc0 = fmaf(f0, cc0, i0 * g0);
            float h0 = o0 * fast_tanh(cc0);
            float i1 = fast_sigmoid(gb[0][1] + bg0), f1 = fast_sigmoid(gb[1][1] + bg1);
            float g1 = fast_tanh(gb[2][1] + bg2),    o1 = fast_sigmoid(gb[3][1] + bg3);
            cc1 = fmaf(f1, cc1, i1 * g1);
            float h1 = o1 * fast_tanh(cc1);

            const unsigned tg = (unsigned)(t & 3);
            const unsigned tu0 = (__float_as_uint(h0) & ~3u) | tg;
            const unsigned tu1 = (__float_as_uint(h1) & ~3u) | tg;

            // stage x(t+1): private always; shared by uw==0 BEFORE publish (ordering)
            if (is_st && t + 1 < T_LEN) {
                xown[uw][(t + 1) & 1][0][lane] = xr0;
                xown[uw][(t + 1) & 1][1][lane] = xr1;
                if (uw == 0) {
                    x_lds[(t + 1) & 1][0][lane] = xr0;
                    x_lds[(t + 1) & 1][1][lane] = xr1;
                }
            }
            asm volatile("s_waitcnt lgkmcnt(0)" ::: "memory");  // x visible pre-publish

            // publish this batch's tagged h dword
            const unsigned tuu = uw ? tu1 : tu0;
            float* dst = hg + (t & 1) * 512 + (s * 64 + j) * 2 + uw;
            asm volatile("global_store_dword %0, %1, off sc0 sc1"
                         :: "v"(dst), "v"(tuu) : "memory");

            // own-h private copy (tagged, both batches) for next step's FMA
            float2v hw; hw.x = __uint_as_float(tu0); hw.y = __uint_as_float(tu1);
            *(float2v*)&hown[uw][t & 1][j][0] = hw;

            // off-path outputs
            const float hvu = uw ? h1 : h0;
            outs[((size_t)(batch0 + uw) * T_LEN + t) * H_DIM + s * 64 + j] =
                __float2bfloat16(hvu);
            if (t == T_LEN - 1) {
                out_c[(batch0 + uw) * H_DIM + s * 64 + j] = uw ? cc1 : cc0;
                out_h[(batch0 + uw) * H_DIM + s * 64 + j] = hvu;
            }
            // prefetch x(t+2)
            if (is_st && t + 2 < T_LEN) {
                const int k = lane;
                const size_t r0 = (size_t)(batch0 + 0) * T_LEN;
                const size_t r1 = (size_t)(batch0 + 1) * T_LEN;
                xr0 = (k < 32) ? z_t[(r0 + t + 2) * 32 + k] : a_t[(r0 + t + 2) * 3 + (k - 32)];
                xr1 = (k < 32) ? z_t[(r1 + t + 2) * 32 + k] : a_t[(r1 + t + 2) * 3 + (k - 32)];
            }
        }
        // pollers loop straight to the next poll (they only touch parity (t)&1 next)
    }
}

// mdn = outputs(bf16) @ Wd + bd, fused log_softmax(log_pi) and exp(log_sigma)+1e-6.
__global__ __launch_bounds__(256, 1) void mdn_kernel(
    const unsigned short* __restrict__ outputs, const float* __restrict__ Wd,
    const float* __restrict__ bd, float* __restrict__ out)
{
    __shared__ __align__(16) float hT[H_DIM * 16];   // hT[k*16 + r]
    __shared__ float lp[16][K_MIX];

    const int tid = threadIdx.x;
    const long row0 = (long)blockIdx.x * 16;

    for (int idx = tid; idx < H_DIM * 16; idx += 256) {
        int r = idx >> 8;
        int k = idx & (H_DIM - 1);
        unsigned int u = outputs[(row0 + r) * H_DIM + k];
        hT[k * 16 + r] = __uint_as_float(u << 16);
    }
    __syncthreads();

    const int  cA = tid;
    const int  cB = tid + 256;
    const bool vB = (cB < MDN_D);
    const float bA = bd[cA];
    const float bB = vB ? bd[cB] : 0.0f;
    float accA[16], accB[16];
    #pragma unroll
    for (int r = 0; r < 16; ++r) { accA[r] = bA; accB[r] = bB; }

    for (int k = 0; k < H_DIM; ++k) {
        float wA = Wd[(size_t)k * MDN_D + cA];
        float wB = vB ? Wd[(size_t)k * MDN_D + cB] : 0.0f;
        const float4* hp = (const float4*)(hT + k * 16);
        float4 h0 = hp[0], h1 = hp[1], h2 = hp[2], h3 = hp[3];
        float hr[16] = { h0.x,h0.y,h0.z,h0.w, h1.x,h1.y,h1.z,h1.w,
                         h2.x,h2.y,h2.z,h2.w, h3.x,h3.y,h3.z,h3.w };
        #pragma unroll
        for (int r = 0; r < 16; ++r) {
            accA[r] = fmaf(hr[r], wA, accA[r]);
            accB[r] = fmaf(hr[r], wB, accB[r]);
        }
    }

    float* out_mu = out + OFF_MU;
    float* out_sg = out + OFF_SIGMA;
    #pragma unroll
    for (int r = 0; r < 16; ++r) {
        long row = row0 + r;
        float v = accA[r];
        if (cA < K_MIX)            lp[r][cA] = v;
        else if (cA < K_MIX + 160) out_mu[row * 160 + (cA - K_MIX)] = v;
        else                       out_sg[row * 160 + (cA - 165)]   = __expf(v) + 1e-6f;
        if (vB)                    out_sg[row * 160 + (cB - 165)]   = __expf(accB[r]) + 1e-6f;
    }
    __syncthreads();

    if (tid < 16) {
        int r = tid;
        long row = row0 + r;
        float v0 = lp[r][0], v1 = lp[r][1], v2 = lp[r][2], v3 = lp[r][3], v4 = lp[r][4];
        float m = fmaxf(fmaxf(fmaxf(v0, v1), fmaxf(v2, v3)), v4);
        float sum = __expf(v0-m) + __expf(v1-m) + __expf(v2-m) + __expf(v3-m) + __expf(v4-m);
        float ls = m + __logf(sum);
        out[row*5 + 0] = v0 - ls;
        out[row*5 + 1] = v1 - ls;
        out[row*5 + 2] = v2 - ls;
        out[row*5 + 3] = v3 - ls;
        out[row*5 + 4] = v4 - ls;
    }
}

extern "C" void kernel_launch(void* const* d_in, const int* in_sizes, int n_in,
                              void* d_out, int out_size, void* d_ws, size_t ws_size,
                              hipStream_t stream)
{
    const float* z_t = (const float*)d_in[0];
    const float* a_t = (const float*)d_in[1];
    const float* Wx  = (const float*)d_in[2];
    const float* Wh  = (const float*)d_in[3];
    const float* b   = (const float*)d_in[4];
    const float* Wd  = (const float*)d_in[5];
    const float* bd  = (const float*)d_in[6];
    float* out = (float*)d_out;

    char* ws = (char*)d_ws;
    __hip_bfloat16* outs = (__hip_bfloat16*)(ws + WS_OUT);
    float* h_glb         = (float*)(ws + WS_HG);

    lstm8_kernel<<<NGRP * NSLICE, 512, 0, stream>>>(z_t, a_t, Wx, Wh, b,
                                                    h_glb, outs,
                                                    out + OFF_C, out + OFF_H);
    mdn_kernel<<<(B_SZ * T_LEN) / 16, 256, 0, stream>>>((const unsigned short*)outs,
                                                        Wd, bd, out);
}

// Round 9
// 1233.538 us; speedup vs baseline: 1.5061x; 1.1148x over previous
//
#include <hip/hip_runtime.h>
#include <hip/hip_bf16.h>
#include <math.h>

// MDN-RNN: B=128, T=512, Z=32, A=3, H=256, K=5, IN=35, 4H=1024, MDN=325
#define T_LEN 512
#define B_SZ  128
#define H_DIM 256
#define G_DIM 1024
#define IN_D  35
#define MDN_D 325
#define K_MIX 5

#define NSLICE 4     // gate-dim slices per group (each owns 64 h-cols x 4 gates)
#define BG     2     // batches per group
#define NGRP   64    // 128 / BG   -> 256 blocks total = 1/CU

// d_out layout: log_pi[B,T,5] | mu[B,T,5,32] | sigma[B,T,5,32] | c[B,256] | h[B,256]
static constexpr long OFF_MU    = 327680L;
static constexpr long OFF_SIGMA = 10813440L;
static constexpr long OFF_C     = 21299200L;
static constexpr long OFF_H     = 21331968L;

// ws layout (~34 MB; ws >= 64 MiB proven in round 1)
static constexpr size_t WS_OUT = 0;          // bf16 outs: B*T*H*2 = 33,554,432 B
static constexpr size_t WS_HG  = 33554432;   // 64 grp * 2 par * 2 b * 256 f32 = 512 KB

typedef unsigned uint2v  __attribute__((ext_vector_type(2)));
typedef float    float2v __attribute__((ext_vector_type(2)));
typedef float    float4v __attribute__((ext_vector_type(4)));

__device__ __forceinline__ float fast_sigmoid(float x) { return 1.0f / (1.0f + __expf(-x)); }
__device__ __forceinline__ float fast_tanh(float x) {
    return 1.0f - 2.0f / (__expf(2.0f * x) + 1.0f);
}

// acc.lo += w.lo*h.lo ; acc.hi += w.hi*h.lo   (broadcast LOW half of h-pair)
__device__ __forceinline__ void pk_fma_lo(float2v& acc, float2v w, float2v h) {
    asm("v_pk_fma_f32 %0, %1, %2, %0 op_sel:[0,0,0] op_sel_hi:[1,0,1]"
        : "+v"(acc) : "v"(w), "v"(h));
}
// acc.lo += w.lo*h.hi ; acc.hi += w.hi*h.hi   (broadcast HIGH half of h-pair)
__device__ __forceinline__ void pk_fma_hi(float2v& acc, float2v w, float2v h) {
    asm("v_pk_fma_f32 %0, %1, %2, %0 op_sel:[0,1,0] op_sel_hi:[1,1,1]"
        : "+v"(acc) : "v"(w), "v"(h));
}

// r6 structure (proven 1085us) with ONE change: 2-deep pipelined polling.
// 256 blocks (group=bid&63, slice=bid>>6), 512 threads; weights VGPR-resident
// (pinned). Waves 0-1 = writers (publish tagged h, never poll), waves 2-4 =
// pollers (pure: zero stores -> no ack pollution; 2 probes in flight, check the
// older via register-tied vmcnt(1) -> probe spacing ~halved), wave 6 = x stagers.
__global__ __launch_bounds__(512, 1) void lstm9_kernel(
    const float* __restrict__ z_t, const float* __restrict__ a_t,
    const float* __restrict__ Wx,  const float* __restrict__ Wh,
    const float* __restrict__ bias,
    float* __restrict__ h_glb,
    __hip_bfloat16* __restrict__ outs,
    float* __restrict__ out_c, float* __restrict__ out_h)
{
    const int bid = blockIdx.x;
    const int gr  = bid & 63;
    const int s   = bid >> 6;
    const int tid = threadIdx.x;
    const int cg  = tid >> 2;              // cols {2cg, 2cg+1} of this 256-col slice
    const int kq  = tid & 3;               // k-range [kq*64, kq*64+64)
    const int lc0 = cg * 2;
    const int gate = lc0 >> 6;
    const int j0   = lc0 & 63;
    const int gcol0 = gate * 256 + s * 64 + j0;

    __shared__ __align__(16) float h_lds[BG][4][68];   // kq sections padded (+4)
    __shared__ __align__(16) float x_lds[2][BG][44];   // double-buffered x
    __shared__ __align__(16) float g_red[BG][256];

    for (int i = tid; i < BG * 4 * 68; i += 512) ((float*)h_lds)[i] = 0.0f;  // h(-1)=0
    if (tid < 2 * BG * 9) {   // zero x pads [35..43] both parities
        int buf = tid / 18, r = tid % 18, b = r / 9, k = 35 + r % 9;
        x_lds[buf][b][k] = 0.0f;
    }

    // ---- persistent weights in VGPRs (loaded once, pinned vs remat) ----
    float2v W2[64];
    #pragma unroll
    for (int i = 0; i < 64; ++i) {
        const size_t r = (size_t)(kq * 64 + i) * G_DIM;
        W2[i].x = Wh[r + gcol0];
        W2[i].y = Wh[r + gcol0 + 1];
    }
    float2v X2[10];
    #pragma unroll
    for (int i = 0; i < 10; ++i) {
        int xk = kq * 10 + i;
        bool ok = (xk < IN_D);
        X2[i].x = ok ? Wx[(size_t)xk * G_DIM + gcol0]     : 0.0f;
        X2[i].y = ok ? Wx[(size_t)xk * G_DIM + gcol0 + 1] : 0.0f;
    }
    #pragma unroll
    for (int i = 0; i < 64; ++i) asm volatile("" : "+v"(W2[i]));
    #pragma unroll
    for (int i = 0; i < 10; ++i) asm volatile("" : "+v"(X2[i]));

    // writer role (tid<128): batch cb, h-col cj of this slice
    const int cb = tid >> 6;
    const int cj = tid & 63;
    const float bc0 = bias[0 * 256 + s * 64 + cj];
    const float bc1 = bias[1 * 256 + s * 64 + cj];
    const float bc2 = bias[2 * 256 + s * 64 + cj];
    const float bc3 = bias[3 * 256 + s * 64 + cj];
    float c_reg = 0.0f;

    // poller role (tid in [128,320)): q -> foreign dword pair (b, kk)
    const int q  = tid - 128;              // 0..191
    const int pb = (q >= 96) ? 1 : 0;
    const int pp = q - 96 * pb;            // 0..95
    const int pk0 = pp * 2;
    const int pkk = pk0 + ((pk0 >= s * 64) ? 64 : 0);   // skip own slice's 64-chunk

    const int batch0 = gr * BG;
    float* hg = h_glb + (size_t)gr * (2 * BG * H_DIM);   // [2][BG][256]

    // ---- pre-loop: stage x(0) ----
    if (tid >= 384 && tid < 448) {
        int qq = tid - 384, b = qq >> 5, k = qq & 31;
        x_lds[0][b][k] = z_t[((size_t)(batch0 + b) * T_LEN + 0) * 32 + k];
    } else if (tid >= 448 && tid < 448 + BG * 3) {
        int qq = tid - 448, b = (qq >= 3), k = qq - 3 * b;
        x_lds[0][b][32 + k] = a_t[((size_t)(batch0 + b) * T_LEN + 0) * 3 + k];
    }
    __syncthreads();

    for (int t = 0; t < T_LEN; ++t) {
        // ---- (A) 2-deep pipelined poll of foreign tagged h(t-1) pairs ----
        if (t > 0 && tid >= 128 && tid < 320) {
            const unsigned want = (unsigned)((t - 1) & 3);
            const float* ap = hg + ((t - 1) & 1) * (BG * H_DIM) + pb * H_DIM + pkk;
            uint2v u0, u1, got;
            asm volatile("global_load_dwordx2 %0, %1, off sc0 sc1"
                         : "=v"(u0) : "v"(ap) : "memory");
            for (;;) {
                asm volatile("global_load_dwordx2 %0, %1, off sc0 sc1"
                             : "=v"(u1) : "v"(ap) : "memory");
                asm volatile("s_waitcnt vmcnt(1)" : "+v"(u0) :: "memory");
                if ((u0.x & 3u) == want && (u0.y & 3u) == want) { got = u0; break; }
                asm volatile("global_load_dwordx2 %0, %1, off sc0 sc1"
                             : "=v"(u0) : "v"(ap) : "memory");
                asm volatile("s_waitcnt vmcnt(1)" : "+v"(u1) :: "memory");
                if ((u1.x & 3u) == want && (u1.y & 3u) == want) { got = u1; break; }
            }
            asm volatile("s_waitcnt vmcnt(0)" ::: "memory");  // drain the extra probe
            float* dst = &h_lds[pb][pkk >> 6][pkk & 63];
            dst[0] = __uint_as_float(got.x);
            dst[1] = __uint_as_float(got.y);
        }
        __syncthreads();   // B1: h_lds + x_lds(t) ready

        // ---- (B) packed FMA: 2 batches x col-pair x 64 k per thread ----
        float2v acc0 = {0.0f, 0.0f}, acc1 = {0.0f, 0.0f};
        {
            const float4v* hp0 = (const float4v*)h_lds[0][kq];
            const float4v* hp1 = (const float4v*)h_lds[1][kq];
            #pragma unroll
            for (int i4 = 0; i4 < 16; ++i4) {
                float4v hv0 = hp0[i4];
                float4v hv1 = hp1[i4];
                float2v h0lo = __builtin_shufflevector(hv0, hv0, 0, 1);
                float2v h0hi = __builtin_shufflevector(hv0, hv0, 2, 3);
                float2v h1lo = __builtin_shufflevector(hv1, hv1, 0, 1);
                float2v h1hi = __builtin_shufflevector(hv1, hv1, 2, 3);
                pk_fma_lo(acc0, W2[4*i4+0], h0lo); pk_fma_lo(acc1, W2[4*i4+0], h1lo);
                pk_fma_hi(acc0, W2[4*i4+1], h0lo); pk_fma_hi(acc1, W2[4*i4+1], h1lo);
                pk_fma_lo(acc0, W2[4*i4+2], h0hi); pk_fma_lo(acc1, W2[4*i4+2], h1hi);
                pk_fma_hi(acc0, W2[4*i4+3], h0hi); pk_fma_hi(acc1, W2[4*i4+3], h1hi);
            }
            #pragma unroll
            for (int i = 0; i < 5; ++i) {
                float2v xv0 = *(const float2v*)&x_lds[t & 1][0][kq * 10 + 2 * i];
                float2v xv1 = *(const float2v*)&x_lds[t & 1][1][kq * 10 + 2 * i];
                pk_fma_lo(acc0, X2[2*i],   xv0); pk_fma_lo(acc1, X2[2*i],   xv1);
                pk_fma_hi(acc0, X2[2*i+1], xv0); pk_fma_hi(acc1, X2[2*i+1], xv1);
            }
        }
        float a00 = acc0.x, a01 = acc0.y, a10 = acc1.x, a11 = acc1.y;
        // k-reduce across the 4 kq lanes of each quad
        a00 += __shfl_xor(a00, 1, 64); a00 += __shfl_xor(a00, 2, 64);
        a01 += __shfl_xor(a01, 1, 64); a01 += __shfl_xor(a01, 2, 64);
        a10 += __shfl_xor(a10, 1, 64); a10 += __shfl_xor(a10, 2, 64);
        a11 += __shfl_xor(a11, 1, 64); a11 += __shfl_xor(a11, 2, 64);
        if (kq == 0) {
            g_red[0][lc0] = a00; g_red[0][lc0 + 1] = a01;
            g_red[1][lc0] = a10; g_red[1][lc0 + 1] = a11;
        }
        __syncthreads();   // B2: g_red ready; FMA reads of h_lds/x_lds done

        // ---- (C) writers: nonlin + c/h update + tagged publish + local h_lds ----
        if (tid < 128) {
            float gi = g_red[cb][      cj] + bc0;
            float gf = g_red[cb][ 64 + cj] + bc1;
            float gg = g_red[cb][128 + cj] + bc2;
            float go = g_red[cb][192 + cj] + bc3;
            float iv = fast_sigmoid(gi), fv = fast_sigmoid(gf), ov = fast_sigmoid(go);
            float gv = fast_tanh(gg);
            c_reg = fmaf(fv, c_reg, iv * gv);
            float hv = ov * fast_tanh(c_reg);
            unsigned u = (__float_as_uint(hv) & ~3u) | (unsigned)(t & 3);
            float* dst = hg + (t & 1) * (BG * H_DIM) + cb * H_DIM + s * 64 + cj;
            asm volatile("global_store_dword %0, %1, off sc0 sc1"
                         :: "v"(dst), "v"(u) : "memory");
            h_lds[cb][s][cj] = __uint_as_float(u);   // own slice: no IC round trip
            outs[((size_t)(batch0 + cb) * T_LEN + t) * H_DIM + s * 64 + cj] =
                __float2bfloat16(hv);
            if (t == T_LEN - 1) {
                out_c[(batch0 + cb) * H_DIM + s * 64 + cj] = c_reg;
                out_h[(batch0 + cb) * H_DIM + s * 64 + cj] = hv;
            }
        }
        // ---- (C) stagers: x(t+1) -> other parity (FMA readers are past B2) ----
        if (t + 1 < T_LEN) {
            if (tid >= 384 && tid < 448) {
                int qq = tid - 384, b = qq >> 5, k = qq & 31;
                x_lds[(t + 1) & 1][b][k] =
                    z_t[((size_t)(batch0 + b) * T_LEN + (t + 1)) * 32 + k];
            } else if (tid >= 448 && tid < 448 + BG * 3) {
                int qq = tid - 448, b = (qq >= 3), k = qq - 3 * b;
                x_lds[(t + 1) & 1][b][32 + k] =
                    a_t[((size_t)(batch0 + b) * T_LEN + (t + 1)) * 3 + k];
            }
        }
        // next iteration's B1 orders all LDS writes; pollers gate on foreign stores
    }
}

// mdn = outputs(bf16) @ Wd + bd, fused log_softmax / exp epilogues.
// 32 rows per block (Wd L2 traffic halved vs 16), float2 row-pair accumulators
// (clang emits v_pk_fma_f32), 4 blocks/CU for L2-latency hiding.
#define MROWS 32
__global__ __launch_bounds__(256, 4) void mdn2_kernel(
    const unsigned short* __restrict__ outputs, const float* __restrict__ Wd,
    const float* __restrict__ bd, float* __restrict__ out)
{
    __shared__ __align__(16) float hT[H_DIM * 34];   // hT[k*34 + r], pad->b64-aligned
    __shared__ float lp[MROWS][K_MIX];

    const int tid = threadIdx.x;
    const long row0 = (long)blockIdx.x * MROWS;

    // load 32 rows x 256 k (bf16, coalesced), store transposed with pad
    for (int idx = tid; idx < H_DIM * MROWS; idx += 256) {
        int r = idx >> 8;             // iteration index = row
        int k = idx & (H_DIM - 1);    // = tid
        unsigned u = outputs[(row0 + r) * H_DIM + k];
        hT[k * 34 + r] = __uint_as_float(u << 16);
    }
    __syncthreads();

    const int  cA = tid;
    const int  cB = tid + 256;
    const bool vB = (cB < MDN_D);
    const float bA = bd[cA];
    const float bB = vB ? bd[cB] : 0.0f;
    float2v accA[16], accB[16];
    #pragma unroll
    for (int p = 0; p < 16; ++p) {
        accA[p].x = bA; accA[p].y = bA;
        accB[p].x = bB; accB[p].y = bB;
    }

    for (int k = 0; k < H_DIM; ++k) {
        float wA = Wd[(size_t)k * MDN_D + cA];
        float wB = vB ? Wd[(size_t)k * MDN_D + cB] : 0.0f;
        float2v wA2; wA2.x = wA; wA2.y = wA;
        float2v wB2; wB2.x = wB; wB2.y = wB;
        const float2v* hp = (const float2v*)(hT + k * 34);   // uniform -> broadcast
        #pragma unroll
        for (int p = 0; p < 16; ++p) {
            float2v h2 = hp[p];
            accA[p] += h2 * wA2;
            accB[p] += h2 * wB2;
        }
    }

    float* out_mu = out + OFF_MU;
    float* out_sg = out + OFF_SIGMA;
    #pragma unroll
    for (int p = 0; p < 16; ++p) {
        #pragma unroll
        for (int e = 0; e < 2; ++e) {
            long row = row0 + 2 * p + e;
            float v = e ? accA[p].y : accA[p].x;
            if (cA < K_MIX)            lp[2*p+e][cA] = v;
            else if (cA < K_MIX + 160) out_mu[row * 160 + (cA - K_MIX)] = v;
            else                       out_sg[row * 160 + (cA - 165)]   = __expf(v) + 1e-6f;
            if (vB) {
                float vb = e ? accB[p].y : accB[p].x;
                out_sg[row * 160 + (cB - 165)] = __expf(vb) + 1e-6f;
            }
        }
    }
    __syncthreads();

    if (tid < MROWS) {
        int r = tid;
        long row = row0 + r;
        float v0 = lp[r][0], v1 = lp[r][1], v2 = lp[r][2], v3 = lp[r][3], v4 = lp[r][4];
        float m = fmaxf(fmaxf(fmaxf(v0, v1), fmaxf(v2, v3)), v4);
        float sum = __expf(v0-m) + __expf(v1-m) + __expf(v2-m) + __expf(v3-m) + __expf(v4-m);
        float ls = m + __logf(sum);
        out[row*5 + 0] = v0 - ls;
        out[row*5 + 1] = v1 - ls;
        out[row*5 + 2] = v2 - ls;
        out[row*5 + 3] = v3 - ls;
        out[row*5 + 4] = v4 - ls;
    }
}

extern "C" void kernel_launch(void* const* d_in, const int* in_sizes, int n_in,
                              void* d_out, int out_size, void* d_ws, size_t ws_size,
                              hipStream_t stream)
{
    const float* z_t = (const float*)d_in[0];
    const float* a_t = (const float*)d_in[1];
    const float* Wx  = (const float*)d_in[2];
    const float* Wh  = (const float*)d_in[3];
    const float* b   = (const float*)d_in[4];
    const float* Wd  = (const float*)d_in[5];
    const float* bd  = (const float*)d_in[6];
    float* out = (float*)d_out;

    char* ws = (char*)d_ws;
    __hip_bfloat16* outs = (__hip_bfloat16*)(ws + WS_OUT);
    float* h_glb         = (float*)(ws + WS_HG);

    lstm9_kernel<<<NGRP * NSLICE, 512, 0, stream>>>(z_t, a_t, Wx, Wh, b,
                                                    h_glb, outs,
                                                    out + OFF_C, out + OFF_H);
    mdn2_kernel<<<(B_SZ * T_LEN) / MROWS, 256, 0, stream>>>((const unsigned short*)outs,
                                                            Wd, bd, out);
}